// Round 2
// baseline (255.643 us; speedup 1.0000x reference)
//
#include <hip/hip_runtime.h>
#include <stdint.h>

typedef unsigned long long u64;

namespace {
constexpr int kB = 16384;
constexpr int kInF = 1024;
constexpr int kOutF = 1024;
constexpr int kT = 16;
constexpr int kR = 256;

// One 256-thread block handles 2 batch rows (float32 end to end).
// Stage 1: coalesced-load two x rows (2 x 4KB f32) into LDS.
// Stage 2: each of the 4 waves computes 8 table indices via one __ballot:
//          lane = (t_local*8 + c), so byte t_local of the 64-bit ballot
//          mask is exactly idx[t] = sum_c (diff>0)<<c.
// Stage 3: each thread owns 8 output columns; per t it loads 32B from the
//          selected table row (wave-contiguous 2KB), accumulates, then
//          stores 32B of f32 output.
__global__ __launch_bounds__(256, 4)
void lut_hard_sum(const float* __restrict__ x,
                  const float* __restrict__ table,
                  const int* __restrict__ anchors_a,
                  const int* __restrict__ anchors_b,
                  float* __restrict__ out)
{
    __shared__ __align__(16) float xs[2 * kInF];
    __shared__ __align__(8) unsigned char idxs[2 * kT];

    const int tid = threadIdx.x;
    const int b0 = blockIdx.x * 2;

    // ---- stage 1: 8KB of x into LDS, 2 x float4 per thread, coalesced
    {
        const float4* src = reinterpret_cast<const float4*>(x + (size_t)b0 * kInF);
        float4* dst = reinterpret_cast<float4*>(xs);
        dst[tid]       = src[tid];
        dst[tid + 256] = src[tid + 256];
    }
    __syncthreads();

    // ---- stage 2: ballot-packed index computation
    {
        const int wave  = tid >> 6;    // 0..3
        const int lane  = tid & 63;
        const int row   = wave >> 1;   // which of the 2 b-rows
        const int thalf = wave & 1;    // t in [0,8) or [8,16)
        const int p = thalf * 64 + lane;   // flat (t*8 + c) anchor index
        const float* xr = xs + row * kInF;
        const float va = xr[anchors_a[p]];
        const float vb = xr[anchors_b[p]];
        const u64 m = __ballot(va - vb > 0.0f);
        if (lane == 0) {
            *reinterpret_cast<u64*>(idxs + row * kT + thalf * 8) = m;
        }
    }
    __syncthreads();

    // ---- stage 3: gather-sum 16 table rows, 8 f32 cols per thread
    const int row = tid >> 7;       // 0..1
    const int j   = tid & 127;      // column group: cols [8j, 8j+8)
    const unsigned char* myidx = idxs + row * kT;
    float acc[8] = {0.f, 0.f, 0.f, 0.f, 0.f, 0.f, 0.f, 0.f};

#pragma unroll
    for (int t = 0; t < kT; ++t) {
        const int r = myidx[t];
        const float4* p4 = reinterpret_cast<const float4*>(
            table + (((size_t)(t * kR + r)) << 10)) + j * 2;
        const float4 v0 = p4[0];
        const float4 v1 = p4[1];
        acc[0] += v0.x; acc[1] += v0.y; acc[2] += v0.z; acc[3] += v0.w;
        acc[4] += v1.x; acc[5] += v1.y; acc[6] += v1.z; acc[7] += v1.w;
    }

    float4* o = reinterpret_cast<float4*>(out + (size_t)(b0 + row) * kOutF + (size_t)j * 8);
    o[0] = make_float4(acc[0], acc[1], acc[2], acc[3]);
    o[1] = make_float4(acc[4], acc[5], acc[6], acc[7]);
}
} // namespace

extern "C" void kernel_launch(void* const* d_in, const int* in_sizes, int n_in,
                              void* d_out, int out_size, void* d_ws, size_t ws_size,
                              hipStream_t stream) {
    const float* x     = (const float*)d_in[0];
    const float* table = (const float*)d_in[1];
    const int*   aa    = (const int*)d_in[2];
    const int*   ab    = (const int*)d_in[3];
    float* out = (float*)d_out;

    dim3 grid(kB / 2);
    dim3 block(256);
    hipLaunchKernelGGL(lut_hard_sum, grid, block, 0, stream, x, table, aa, ab, out);
}

// Round 3
// 155.943 us; speedup vs baseline: 1.6393x; 1.6393x over previous
//
#include <hip/hip_runtime.h>
#include <stdint.h>

typedef unsigned int u32;
typedef unsigned long long u64;

namespace {
constexpr int kB = 16384;
constexpr int kInF = 1024;
constexpr int kOutF = 1024;
constexpr int kT = 16;
constexpr int kR = 256;
constexpr int kG = 32;       // batch rows per gather block
constexpr int kSlices = 8;   // column slices (one per XCD)
constexpr int kSW = kOutF / kSlices;  // 128 cols per slice

// ---------------- Pass 1: compute packed 8-bit indices ----------------
// One 256-thread block per 2 batch rows. LDS-stage x, then one __ballot
// per wave packs 8 indices: lane = t_local*8 + c, so byte t_local of the
// 64-bit mask is idx[t] = sum_c (diff>0)<<c. Lane 0 writes the u64
// (8 packed indices) straight to the workspace.
__global__ __launch_bounds__(256, 4)
void lut_indices(const float* __restrict__ x,
                 const int* __restrict__ anchors_a,
                 const int* __restrict__ anchors_b,
                 u64* __restrict__ idx_out)   // [kB * 2] u64s
{
    __shared__ __align__(16) float xs[2 * kInF];

    const int tid = threadIdx.x;
    const int b0 = blockIdx.x * 2;

    {
        const float4* src = reinterpret_cast<const float4*>(x + (size_t)b0 * kInF);
        float4* dst = reinterpret_cast<float4*>(xs);
        dst[tid]       = src[tid];
        dst[tid + 256] = src[tid + 256];
    }
    __syncthreads();

    const int wave  = tid >> 6;    // 0..3
    const int lane  = tid & 63;
    const int row   = wave >> 1;   // which of the 2 b-rows
    const int thalf = wave & 1;    // t in [0,8) or [8,16)
    const int p = thalf * 64 + lane;   // flat (t*8 + c) anchor index
    const float* xr = xs + row * kInF;
    const float va = xr[anchors_a[p]];
    const float vb = xr[anchors_b[p]];
    const u64 m = __ballot(va - vb > 0.0f);
    if (lane == 0) {
        idx_out[(size_t)(b0 + row) * 2 + thalf] = m;
    }
}

// ---------------- Pass 2: sliced gather-sum ----------------
// blockIdx % 8 = column slice (XCD round-robin => per-XCD table slice is
// 16*256*128*4 = 2.1 MB, fits the 4 MiB L2). Each block: 32 batch rows x
// 128 cols. Indices staged in LDS (broadcast reads, conflict-free).
// Thread (rsub, col4) accumulates a float4 over 16 independent L2 loads.
__global__ __launch_bounds__(256, 4)
void lut_gather(const float* __restrict__ table,
                const unsigned char* __restrict__ idxb,  // [kB][kT]
                float* __restrict__ out)
{
    __shared__ unsigned char lidx[kG][kT];

    const int slice = blockIdx.x & (kSlices - 1);
    const int group = blockIdx.x >> 3;
    const int b0 = group * kG;
    const int tid = threadIdx.x;

    if (tid < (kG * kT / 4)) {   // 128 u32 = 512 B of indices
        reinterpret_cast<u32*>(lidx)[tid] =
            reinterpret_cast<const u32*>(idxb + (size_t)b0 * kT)[tid];
    }
    __syncthreads();

    const int col4 = tid & 31;          // 0..31 -> float4 column group
    const int rsub = tid >> 5;          // 0..7
    const int cbase = slice * kSW + col4 * 4;

#pragma unroll
    for (int rg = 0; rg < kG / 8; ++rg) {
        const int rl = rg * 8 + rsub;
        float4 acc = make_float4(0.f, 0.f, 0.f, 0.f);
#pragma unroll
        for (int t = 0; t < kT; ++t) {
            const int r = lidx[rl][t];
            const float4 v = *reinterpret_cast<const float4*>(
                table + (((size_t)(t * kR + r)) << 10) + cbase);
            acc.x += v.x; acc.y += v.y; acc.z += v.z; acc.w += v.w;
        }
        *reinterpret_cast<float4*>(out + (size_t)(b0 + rl) * kOutF + cbase) = acc;
    }
}
} // namespace

extern "C" void kernel_launch(void* const* d_in, const int* in_sizes, int n_in,
                              void* d_out, int out_size, void* d_ws, size_t ws_size,
                              hipStream_t stream) {
    const float* x     = (const float*)d_in[0];
    const float* table = (const float*)d_in[1];
    const int*   aa    = (const int*)d_in[2];
    const int*   ab    = (const int*)d_in[3];
    float* out = (float*)d_out;

    u64* idx_ws = (u64*)d_ws;   // kB*16 bytes = 256 KB of packed indices

    hipLaunchKernelGGL(lut_indices, dim3(kB / 2), dim3(256), 0, stream,
                       x, aa, ab, idx_ws);
    hipLaunchKernelGGL(lut_gather, dim3((kB / kG) * kSlices), dim3(256), 0, stream,
                       table, (const unsigned char*)d_ws, out);
}

// Round 4
// 149.107 us; speedup vs baseline: 1.7145x; 1.0458x over previous
//
#include <hip/hip_runtime.h>
#include <stdint.h>

typedef unsigned short u16;
typedef unsigned int u32;
typedef unsigned long long u64;

namespace {
constexpr int kB = 16384;
constexpr int kInF = 1024;
constexpr int kOutF = 1024;
constexpr int kT = 16;
constexpr int kR = 256;
constexpr int kG = 32;       // batch rows per gather block
constexpr int kSlices = 8;   // column slices (one per XCD)
constexpr int kSW = kOutF / kSlices;  // 128 cols per slice

constexpr size_t kIdxBytes = (size_t)kB * kT;                    // 256 KB
constexpr size_t kTblElems = (size_t)kT * kR * kOutF;            // 4.19 M
constexpr size_t kTblBf16Bytes = kTblElems * 2;                  // 8.39 MB

// ---------------- Pass 0: table f32 -> bf16 (round-to-nearest-even) --------
__global__ __launch_bounds__(256, 4)
void tbl_to_bf16(const float* __restrict__ table, u16* __restrict__ tb)
{
    const size_t i0 = ((size_t)blockIdx.x * 256 + threadIdx.x) * 8;
    const float4 a = *reinterpret_cast<const float4*>(table + i0);
    const float4 b = *reinterpret_cast<const float4*>(table + i0 + 4);
    const float f[8] = {a.x, a.y, a.z, a.w, b.x, b.y, b.z, b.w};
    u16 h[8];
#pragma unroll
    for (int i = 0; i < 8; ++i) {
        u32 u = __float_as_uint(f[i]);
        u += 0x7fffu + ((u >> 16) & 1u);   // RNE
        h[i] = (u16)(u >> 16);
    }
    uint4 o;
    o.x = h[0] | ((u32)h[1] << 16);
    o.y = h[2] | ((u32)h[3] << 16);
    o.z = h[4] | ((u32)h[5] << 16);
    o.w = h[6] | ((u32)h[7] << 16);
    *reinterpret_cast<uint4*>(tb + i0) = o;
}

// ---------------- Pass 1: packed 8-bit indices via ballot ----------------
__global__ __launch_bounds__(256, 4)
void lut_indices(const float* __restrict__ x,
                 const int* __restrict__ anchors_a,
                 const int* __restrict__ anchors_b,
                 u64* __restrict__ idx_out)   // [kB * 2] u64s
{
    __shared__ __align__(16) float xs[2 * kInF];

    const int tid = threadIdx.x;
    const int b0 = blockIdx.x * 2;

    {
        const float4* src = reinterpret_cast<const float4*>(x + (size_t)b0 * kInF);
        float4* dst = reinterpret_cast<float4*>(xs);
        dst[tid]       = src[tid];
        dst[tid + 256] = src[tid + 256];
    }
    __syncthreads();

    const int wave  = tid >> 6;
    const int lane  = tid & 63;
    const int row   = wave >> 1;
    const int thalf = wave & 1;
    const int p = thalf * 64 + lane;
    const float* xr = xs + row * kInF;
    const float va = xr[anchors_a[p]];
    const float vb = xr[anchors_b[p]];
    const u64 m = __ballot(va - vb > 0.0f);
    if (lane == 0) {
        idx_out[(size_t)(b0 + row) * 2 + thalf] = m;
    }
}

// ---------------- Pass 2: sliced bf16 gather-sum ----------------
// blockIdx % 8 = column slice (per-XCD bf16 slice = 16*256*128*2 = 1.05 MB,
// L2-resident). 256 threads: col8 = tid&15 (8 bf16 cols = one 16B load),
// rsub = tid>>4 (16 rows in flight), kG=32 rows per block in 2 iterations.
__global__ __launch_bounds__(256, 4)
void lut_gather_bf16(const u16* __restrict__ tb,
                     const unsigned char* __restrict__ idxb,  // [kB][kT]
                     float* __restrict__ out)
{
    __shared__ unsigned char lidx[kG][kT];

    const int slice = blockIdx.x & (kSlices - 1);
    const int group = blockIdx.x >> 3;
    const int b0 = group * kG;
    const int tid = threadIdx.x;

    if (tid < (kG * kT / 4)) {
        reinterpret_cast<u32*>(lidx)[tid] =
            reinterpret_cast<const u32*>(idxb + (size_t)b0 * kT)[tid];
    }
    __syncthreads();

    const int col8 = tid & 15;          // 8 bf16 cols per thread
    const int rsub = tid >> 4;          // 0..15
    const int cbase = slice * kSW + col8 * 8;

#pragma unroll
    for (int rg = 0; rg < kG / 16; ++rg) {
        const int rl = rg * 16 + rsub;
        float acc[8] = {0.f, 0.f, 0.f, 0.f, 0.f, 0.f, 0.f, 0.f};
#pragma unroll
        for (int t = 0; t < kT; ++t) {
            const int r = lidx[rl][t];
            const uint4 v = *reinterpret_cast<const uint4*>(
                tb + (((size_t)(t * kR + r)) << 10) + cbase);
            acc[0] += __uint_as_float(v.x << 16);
            acc[1] += __uint_as_float(v.x & 0xffff0000u);
            acc[2] += __uint_as_float(v.y << 16);
            acc[3] += __uint_as_float(v.y & 0xffff0000u);
            acc[4] += __uint_as_float(v.z << 16);
            acc[5] += __uint_as_float(v.z & 0xffff0000u);
            acc[6] += __uint_as_float(v.w << 16);
            acc[7] += __uint_as_float(v.w & 0xffff0000u);
        }
        float4* o = reinterpret_cast<float4*>(
            out + (size_t)(b0 + rl) * kOutF + cbase);
        o[0] = make_float4(acc[0], acc[1], acc[2], acc[3]);
        o[1] = make_float4(acc[4], acc[5], acc[6], acc[7]);
    }
}

// ---------------- Fallback f32 gather (if ws too small) ----------------
__global__ __launch_bounds__(256, 4)
void lut_gather_f32(const float* __restrict__ table,
                    const unsigned char* __restrict__ idxb,
                    float* __restrict__ out)
{
    __shared__ unsigned char lidx[kG][kT];

    const int slice = blockIdx.x & (kSlices - 1);
    const int group = blockIdx.x >> 3;
    const int b0 = group * kG;
    const int tid = threadIdx.x;

    if (tid < (kG * kT / 4)) {
        reinterpret_cast<u32*>(lidx)[tid] =
            reinterpret_cast<const u32*>(idxb + (size_t)b0 * kT)[tid];
    }
    __syncthreads();

    const int col4 = tid & 31;
    const int rsub = tid >> 5;
    const int cbase = slice * kSW + col4 * 4;

#pragma unroll
    for (int rg = 0; rg < kG / 8; ++rg) {
        const int rl = rg * 8 + rsub;
        float4 acc = make_float4(0.f, 0.f, 0.f, 0.f);
#pragma unroll
        for (int t = 0; t < kT; ++t) {
            const int r = lidx[rl][t];
            const float4 v = *reinterpret_cast<const float4*>(
                table + (((size_t)(t * kR + r)) << 10) + cbase);
            acc.x += v.x; acc.y += v.y; acc.z += v.z; acc.w += v.w;
        }
        *reinterpret_cast<float4*>(out + (size_t)(b0 + rl) * kOutF + cbase) = acc;
    }
}
} // namespace

extern "C" void kernel_launch(void* const* d_in, const int* in_sizes, int n_in,
                              void* d_out, int out_size, void* d_ws, size_t ws_size,
                              hipStream_t stream) {
    const float* x     = (const float*)d_in[0];
    const float* table = (const float*)d_in[1];
    const int*   aa    = (const int*)d_in[2];
    const int*   ab    = (const int*)d_in[3];
    float* out = (float*)d_out;

    u64* idx_ws = (u64*)d_ws;                          // 256 KB packed indices
    u16* tb     = (u16*)((char*)d_ws + kIdxBytes);     // 8.39 MB bf16 table

    hipLaunchKernelGGL(lut_indices, dim3(kB / 2), dim3(256), 0, stream,
                       x, aa, ab, idx_ws);

    if (ws_size >= kIdxBytes + kTblBf16Bytes) {
        hipLaunchKernelGGL(tbl_to_bf16, dim3(kTblElems / (256 * 8)), dim3(256),
                           0, stream, table, tb);
        hipLaunchKernelGGL(lut_gather_bf16, dim3((kB / kG) * kSlices), dim3(256),
                           0, stream, tb, (const unsigned char*)d_ws, out);
    } else {
        hipLaunchKernelGGL(lut_gather_f32, dim3((kB / kG) * kSlices), dim3(256),
                           0, stream, table, (const unsigned char*)d_ws, out);
    }
}

// Round 5
// 148.209 us; speedup vs baseline: 1.7249x; 1.0061x over previous
//
#include <hip/hip_runtime.h>
#include <hip/hip_fp16.h>
#include <stdint.h>

typedef unsigned short u16;
typedef unsigned int u32;
typedef unsigned long long u64;

namespace {
constexpr int kB = 16384;
constexpr int kInF = 1024;
constexpr int kOutF = 1024;
constexpr int kT = 16;
constexpr int kR = 256;
constexpr int kG = 32;       // batch rows per gather block
constexpr int kSlices = 8;   // column slices (one per XCD)
constexpr int kSW = kOutF / kSlices;  // 128 cols per slice

constexpr size_t kIdxBytes = (size_t)kB * kT;                    // 256 KB
constexpr size_t kTblElems = (size_t)kT * kR * kOutF;            // 4.19 M
constexpr size_t kTblF16Bytes = kTblElems * 2;                   // 8.39 MB

constexpr int kIdxBlocks = kB / 2;                   // 8192
constexpr int kCvtBlocks = (int)(kTblElems / (256 * 8)); // 2048

// ---------------- Fused pass 1: indices (ballot-packed) + table f32->fp16 --
// Blocks [0, kIdxBlocks): one block per 2 batch rows. LDS-stage x; one
// __ballot per wave packs 8 indices (lane = t_local*8 + c => byte t_local of
// the 64-bit mask is idx[t]).
// Blocks [kIdxBlocks, kIdxBlocks+kCvtBlocks): convert 2048 f32 table elems
// per block to fp16 (RNE). Both are HBM-bound and run concurrently.
__global__ __launch_bounds__(256, 4)
void lut_prep(const float* __restrict__ x,
              const float* __restrict__ table,
              const int* __restrict__ anchors_a,
              const int* __restrict__ anchors_b,
              u64* __restrict__ idx_out,      // [kB*2]
              u16* __restrict__ tf)           // fp16 table
{
    __shared__ __align__(16) float xs[2 * kInF];
    const int tid = threadIdx.x;

    if (blockIdx.x < kIdxBlocks) {
        const int b0 = blockIdx.x * 2;
        {
            const float4* src = reinterpret_cast<const float4*>(x + (size_t)b0 * kInF);
            float4* dst = reinterpret_cast<float4*>(xs);
            dst[tid]       = src[tid];
            dst[tid + 256] = src[tid + 256];
        }
        __syncthreads();

        const int wave  = tid >> 6;
        const int lane  = tid & 63;
        const int row   = wave >> 1;
        const int thalf = wave & 1;
        const int p = thalf * 64 + lane;
        const float* xr = xs + row * kInF;
        const float va = xr[anchors_a[p]];
        const float vb = xr[anchors_b[p]];
        const u64 m = __ballot(va - vb > 0.0f);
        if (lane == 0) {
            idx_out[(size_t)(b0 + row) * 2 + thalf] = m;
        }
    } else {
        const size_t i0 = ((size_t)(blockIdx.x - kIdxBlocks) * 256 + tid) * 8;
        const float4 a = *reinterpret_cast<const float4*>(table + i0);
        const float4 b = *reinterpret_cast<const float4*>(table + i0 + 4);
        __half2 h0 = __floats2half2_rn(a.x, a.y);
        __half2 h1 = __floats2half2_rn(a.z, a.w);
        __half2 h2 = __floats2half2_rn(b.x, b.y);
        __half2 h3 = __floats2half2_rn(b.z, b.w);
        uint4 o;
        o.x = *reinterpret_cast<u32*>(&h0);
        o.y = *reinterpret_cast<u32*>(&h1);
        o.z = *reinterpret_cast<u32*>(&h2);
        o.w = *reinterpret_cast<u32*>(&h3);
        *reinterpret_cast<uint4*>(tf + i0) = o;
    }
}

// ---------------- Pass 2: sliced fp16 gather-sum (v_pk_add_f16) ----------
// blockIdx % 8 = column slice (per-XCD fp16 slice = 16*256*128*2 = 1.05 MB,
// L2-resident via round-robin block->XCD dispatch). 256 threads:
// col8 = tid&15 (8 fp16 cols = one 16B load), rsub = tid>>4 (16 rows),
// kG=32 rows per block in 2 passes. Accumulate in packed fp16 (4 v_pk_add_f16
// per 16B load — vmem-bound, not VALU-bound), widen to f32 at the end.
__global__ __launch_bounds__(256, 4)
void lut_gather_f16(const u16* __restrict__ tf,
                    const unsigned char* __restrict__ idxb,  // [kB][kT]
                    float* __restrict__ out)
{
    __shared__ unsigned char lidx[kG][kT];

    const int slice = blockIdx.x & (kSlices - 1);
    const int group = blockIdx.x >> 3;
    const int b0 = group * kG;
    const int tid = threadIdx.x;

    if (tid < (kG * kT / 4)) {
        reinterpret_cast<u32*>(lidx)[tid] =
            reinterpret_cast<const u32*>(idxb + (size_t)b0 * kT)[tid];
    }
    __syncthreads();

    const int col8 = tid & 15;          // 8 fp16 cols per thread
    const int rsub = tid >> 4;          // 0..15
    const int cbase = slice * kSW + col8 * 8;

#pragma unroll
    for (int rg = 0; rg < kG / 16; ++rg) {
        const int rl = rg * 16 + rsub;
        __half2 acc0 = __half2half2(__ushort_as_half(0));
        __half2 acc1 = acc0, acc2 = acc0, acc3 = acc0;
#pragma unroll
        for (int t = 0; t < kT; ++t) {
            const int r = lidx[rl][t];
            union { uint4 u; __half2 h[4]; } v;
            v.u = *reinterpret_cast<const uint4*>(
                tf + (((size_t)(t * kR + r)) << 10) + cbase);
            acc0 = __hadd2(acc0, v.h[0]);
            acc1 = __hadd2(acc1, v.h[1]);
            acc2 = __hadd2(acc2, v.h[2]);
            acc3 = __hadd2(acc3, v.h[3]);
        }
        const float2 f0 = __half22float2(acc0);
        const float2 f1 = __half22float2(acc1);
        const float2 f2 = __half22float2(acc2);
        const float2 f3 = __half22float2(acc3);
        float4* o = reinterpret_cast<float4*>(
            out + (size_t)(b0 + rl) * kOutF + cbase);
        o[0] = make_float4(f0.x, f0.y, f1.x, f1.y);
        o[1] = make_float4(f2.x, f2.y, f3.x, f3.y);
    }
}

// ---------------- Fallback f32 gather (if ws too small) ----------------
__global__ __launch_bounds__(256, 4)
void lut_gather_f32(const float* __restrict__ table,
                    const unsigned char* __restrict__ idxb,
                    float* __restrict__ out)
{
    __shared__ unsigned char lidx[kG][kT];

    const int slice = blockIdx.x & (kSlices - 1);
    const int group = blockIdx.x >> 3;
    const int b0 = group * kG;
    const int tid = threadIdx.x;

    if (tid < (kG * kT / 4)) {
        reinterpret_cast<u32*>(lidx)[tid] =
            reinterpret_cast<const u32*>(idxb + (size_t)b0 * kT)[tid];
    }
    __syncthreads();

    const int col4 = tid & 31;
    const int rsub = tid >> 5;
    const int cbase = slice * kSW + col4 * 4;

#pragma unroll
    for (int rg = 0; rg < kG / 8; ++rg) {
        const int rl = rg * 8 + rsub;
        float4 acc = make_float4(0.f, 0.f, 0.f, 0.f);
#pragma unroll
        for (int t = 0; t < kT; ++t) {
            const int r = lidx[rl][t];
            const float4 v = *reinterpret_cast<const float4*>(
                table + (((size_t)(t * kR + r)) << 10) + cbase);
            acc.x += v.x; acc.y += v.y; acc.z += v.z; acc.w += v.w;
        }
        *reinterpret_cast<float4*>(out + (size_t)(b0 + rl) * kOutF + cbase) = acc;
    }
}
} // namespace

extern "C" void kernel_launch(void* const* d_in, const int* in_sizes, int n_in,
                              void* d_out, int out_size, void* d_ws, size_t ws_size,
                              hipStream_t stream) {
    const float* x     = (const float*)d_in[0];
    const float* table = (const float*)d_in[1];
    const int*   aa    = (const int*)d_in[2];
    const int*   ab    = (const int*)d_in[3];
    float* out = (float*)d_out;

    u64* idx_ws = (u64*)d_ws;                          // 256 KB packed indices
    u16* tf     = (u16*)((char*)d_ws + kIdxBytes);     // 8.39 MB fp16 table

    if (ws_size >= kIdxBytes + kTblF16Bytes) {
        hipLaunchKernelGGL(lut_prep, dim3(kIdxBlocks + kCvtBlocks), dim3(256),
                           0, stream, x, table, aa, ab, idx_ws, tf);
        hipLaunchKernelGGL(lut_gather_f16, dim3((kB / kG) * kSlices), dim3(256),
                           0, stream, tf, (const unsigned char*)d_ws, out);
    } else {
        hipLaunchKernelGGL(lut_prep, dim3(kIdxBlocks), dim3(256),
                           0, stream, x, table, aa, ab, idx_ws, tf);
        hipLaunchKernelGGL(lut_gather_f32, dim3((kB / kG) * kSlices), dim3(256),
                           0, stream, table, (const unsigned char*)d_ws, out);
    }
}